// Round 2
// baseline (82.095 us; speedup 1.0000x reference)
//
#include <hip/hip_runtime.h>
#include <cmath>

#define NV    8                 // variables
#define NM    42                // coefficients per variable (degree + p - 1)
#define NK    46                // knots per variable (degree + 2p)
#define TOT_C (NM * NV)         // 336
#define NRK   39                // distinct clamped k values: k-3 in [0, 39)
#define NRECS (NV * NRK)        // 312 records
#define REC_F 4                 // floats per record (16 B, aligned)
#define TPB   512               // threads per block
#define EPT   8                 // elements per thread (one full v-cycle)

typedef float f32x4 __attribute__((ext_vector_type(4)));

// ---------------------------------------------------------------------------
// Single fused kernel, uniform-knot cardinal B-spline.
// Key identity (knots are exact linspace, spacing d):
//   q[j] = 3*(c[j+1]-c[j])/(t[j+4]-t[j+1]) = (c[j+1]-c[j]) * invd
//   => log(dy) = log(w0*d0 + w1*d1 + w2*d2) + log(invd_v),  d_j = c[j+1]-c[j]
// so the per-element gather is ONE aligned ds_read_b128 of {c[k-3..k]}.
// Record dword index = 4*(v*39+kk)+i: 4kk mod 32 walks 8 quad-groups, i covers
// each quad -> 64 lanes x 4 dwords spread over all 32 banks (8/bank floor).
// 8 consecutive elements/thread => v == e compile-time; t0/invd/log_invd in
// registers. x loads and y/ld stores are nontemporal float4 (pure streaming).
// ---------------------------------------------------------------------------
__global__ __launch_bounds__(TPB) void fused_kernel(
        const float* __restrict__ x,
        const float* __restrict__ raw,
        const float* __restrict__ knots,
        float* __restrict__ y_out,
        float* __restrict__ ld_out,
        int total)
{
    __shared__ float s[TOT_C];
    __shared__ __align__(16) float rec[NRECS * REC_F];   // 4992 B

    int tid = threadIdx.x;

    // ---- incr = [raw0, softplus(raw[1:])] --------------------------------
    if (tid < TOT_C) {
        float r = raw[tid];
        float inc = (tid < NV) ? r
                  : ((r > 0.f) ? (r + log1pf(expf(-r))) : log1pf(expf(r)));
        s[tid] = inc;
    }
    __syncthreads();

    // ---- cumsum over j (rows of 8 vars), Hillis-Steele -------------------
    for (int off = 1; off < NM; off <<= 1) {
        float a = 0.f;
        if (tid < TOT_C) {
            int j = tid >> 3;
            a = s[tid] + ((j >= off) ? s[tid - off * NV] : 0.f);
        }
        __syncthreads();
        if (tid < TOT_C) s[tid] = a;
        __syncthreads();
    }

    // ---- build 16-B records: {c[kk..kk+3]} -------------------------------
    if (tid < NRECS) {
        int v  = tid / NRK;          // const-divide -> magic mul
        int kk = tid - v * NRK;
        f32x4 cc = { s[(kk + 0) * NV + v],
                     s[(kk + 1) * NV + v],
                     s[(kk + 2) * NV + v],
                     s[(kk + 3) * NV + v] };
        *(f32x4*)&rec[tid * REC_F] = cc;
    }
    __syncthreads();

    // ---- per-thread uniform tables (compile-time indexed => registers) ---
    float t0v[NV], invdv[NV], linvd[NV];
    #pragma unroll
    for (int v = 0; v < NV; ++v) {
        float t0 = knots[v];                 // uniform -> scalar-cached
        float id = 1.f / (knots[NV + v] - t0);
        t0v[v]   = t0;
        invdv[v] = id;
        linvd[v] = __logf(id);
    }

    const float k6 = 0.16666666666f;
    int i0 = (blockIdx.x * TPB + tid) * EPT;     // multiple of 8 => v == e

    if (i0 + EPT - 1 < total) {
        f32x4 xa = __builtin_nontemporal_load((const f32x4*)(x + i0));
        f32x4 xb = __builtin_nontemporal_load((const f32x4*)(x + i0 + 4));
        f32x4 ya, yb, la, lb;
        #pragma unroll
        for (int e = 0; e < EPT; ++e) {
            float xe = (e < 4) ? xa[e] : xb[e - 4];
            const int v = e;
            float f = (xe - t0v[v]) * invdv[v];
            int k = (int)floorf(f);
            k = min(max(k, 3), NK - 5);          // clip to [3, 41]
            float u = f - (float)k;              // extrapolates when clamped,
                                                 // same as deBoor
            f32x4 cc = *(const f32x4*)&rec[(v * NRK + (k - 3)) * REC_F];

            float omu = 1.f - u;
            float u2 = u * u,  o2 = omu * omu;
            float u3 = u2 * u, o3 = o2 * omu;
            float B0 = o3 * k6;
            float B3 = u3 * k6;
            float B1 = (3.f * u3 - 6.f * u2 + 4.f) * k6;
            float B2 = 1.f - B0 - B1 - B3;       // partition of unity
            float yv = fmaf(B0, cc.x, fmaf(B1, cc.y, fmaf(B2, cc.z, B3 * cc.w)));

            float d0 = cc.y - cc.x, d1 = cc.z - cc.y, d2 = cc.w - cc.z;
            float w0 = 0.5f * o2, w2 = 0.5f * u2, w1 = 1.f - w0 - w2;
            float lv = __logf(fmaf(w0, d0, fmaf(w1, d1, w2 * d2))) + linvd[v];

            if (e < 4) { ya[e] = yv; la[e] = lv; }
            else       { yb[e - 4] = yv; lb[e - 4] = lv; }
        }
        __builtin_nontemporal_store(ya, (f32x4*)(y_out + i0));
        __builtin_nontemporal_store(yb, (f32x4*)(y_out + i0 + 4));
        __builtin_nontemporal_store(la, (f32x4*)(ld_out + i0));
        __builtin_nontemporal_store(lb, (f32x4*)(ld_out + i0 + 4));
    } else {
        for (int i = i0; i < total; ++i) {
            int v = i & (NV - 1);
            float t0 = knots[v];
            float invd = 1.f / (knots[NV + v] - t0);
            float f = (x[i] - t0) * invd;
            int k = (int)floorf(f);
            k = min(max(k, 3), NK - 5);
            float u = f - (float)k;
            const float* rp = &rec[(v * NRK + (k - 3)) * REC_F];
            float c0 = rp[0], c1 = rp[1], c2 = rp[2], c3 = rp[3];
            float omu = 1.f - u;
            float u2 = u * u,  o2 = omu * omu;
            float u3 = u2 * u, o3 = o2 * omu;
            float B0 = o3 * k6;
            float B3 = u3 * k6;
            float B1 = (3.f * u3 - 6.f * u2 + 4.f) * k6;
            float B2 = 1.f - B0 - B1 - B3;
            y_out[i] = fmaf(B0, c0, fmaf(B1, c1, fmaf(B2, c2, B3 * c3)));
            float w0 = 0.5f * o2, w2 = 0.5f * u2, w1 = 1.f - w0 - w2;
            float dd = fmaf(w0, c1 - c0, fmaf(w1, c2 - c1, w2 * (c3 - c2)));
            ld_out[i] = __logf(dd) + __logf(invd);
        }
    }
}

extern "C" void kernel_launch(void* const* d_in, const int* in_sizes, int n_in,
                              void* d_out, int out_size, void* d_ws, size_t ws_size,
                              hipStream_t stream) {
    const float* x     = (const float*)d_in[0];
    const float* raw   = (const float*)d_in[1];
    const float* knots = (const float*)d_in[2];

    int total = in_sizes[0];             // N*V = 4,000,000
    float* y_out  = (float*)d_out;
    float* ld_out = y_out + total;

    int threads_needed = (total + EPT - 1) / EPT;
    int blocks = (threads_needed + TPB - 1) / TPB;
    fused_kernel<<<blocks, TPB, 0, stream>>>(x, raw, knots, y_out, ld_out, total);
}